// Round 9
// baseline (228.981 us; speedup 1.0000x reference)
//
#include <hip/hip_runtime.h>

// GSKAN layer: out[b,q] = sum_p prelu(x[b,p] + eps[q]) * Lam[p,q]
// prelu(s) = c1*s + c2*|s|,  c1 = (1+a)/2, c2 = (1-a)/2  (|s| = free VOP3 modifier)
//
// R9: single kernel per layer, NO p-split partial buffers, NO combine kernels.
// Block = 512 threads = 2 halves of 256; half h covers p in [h*n_in/2,(h+1)*n_in/2)
// with the R6-proven 4(b)x{2,1}(q)-per-thread structure over a 64(b)xQTILE(q) tile.
// Half 1 deposits its partial result in LDS; half 0 adds + writes Y (deterministic).
// Register-staged ping-pong LDS double buffer: next chunk's global loads are
// issued BEFORE the FMA block, ds_writes after -> HBM latency hides under compute,
// one barrier per chunk. Grid = (n_out/QTILE)*(B/64) = 256 blocks = 1 block/CU.

#define PCHUNK 32
#define XS_STRIDE 36   // 64-row X tile, pad -> 4 rows/thread on distinct bank quads

template<int QPER>   // q-values per thread; QTILE = 16*QPER
__global__ __launch_bounds__(512, 2) void gskan_layer_kernel(
    const float* __restrict__ X,     // [B][n_in]
    const float* __restrict__ Lam,   // [n_in][n_out]
    const float* __restrict__ Eps,   // [n_out]
    const float* __restrict__ Aw,    // [1]
    float* __restrict__ Y,           // [B][n_out]
    int B, int n_in, int n_out, int NB)
{
    constexpr int QTILE = 16 * QPER;
    __shared__ float xs[2][2][64 * XS_STRIDE];        // [half][buf][row*36+p]
    __shared__ float ls[2][2][PCHUNK * QTILE];        // [half][buf][p*QTILE+q]
    __shared__ float red[64 * (QTILE + 1)];           // half-1 partials, padded stride

    const int tid  = threadIdx.x;
    const int half = tid >> 8;        // 0 or 1 (wave-uniform)
    const int t    = tid & 255;
    const int qg   = t & 15;          // q-group
    const int bl   = t >> 4;          // b-group of 4 rows

    const int b_tile = blockIdx.x % NB;     // consecutive blocks share q_tile ->
    const int q_tile = blockIdx.x / NB;     // XCD round-robin spreads b-panels
    const int b0 = b_tile * 64;
    const int q0 = q_tile * QTILE;

    const float a  = Aw[0];
    const float c1 = 0.5f * (1.0f + a);
    const float c2 = 0.5f * (1.0f - a);

    float ee[QPER];
    #pragma unroll
    for (int j = 0; j < QPER; ++j) ee[j] = Eps[q0 + qg * QPER + j];

    const int pbase  = half * (n_in >> 1);
    const int nchunk = (n_in >> 1) / PCHUNK;

    // staging assignments (per half's 256 threads)
    const int  xrow = t >> 3, xpg = t & 7;                       // X: 2 rows (+0,+32)
    const int  lrow = (QPER == 2) ? (t >> 3) : (t >> 2);         // Lam tile rows
    const int  lc4  = (QPER == 2) ? (t & 7)  : (t & 3);
    const bool lact = (QPER == 2) ? true : (t < 128);

    float (*xsb)[64 * XS_STRIDE] = xs[half];
    float (*lsb)[PCHUNK * QTILE] = ls[half];

    // prologue: stage chunk 0 into buffer 0
    {
        const int pc = pbase;
        float4 v0 = *reinterpret_cast<const float4*>(
            X + (size_t)(b0 + xrow) * n_in + pc + xpg * 4);
        float4 v1 = *reinterpret_cast<const float4*>(
            X + (size_t)(b0 + xrow + 32) * n_in + pc + xpg * 4);
        *reinterpret_cast<float4*>(&xsb[0][xrow * XS_STRIDE + xpg * 4]) = v0;
        *reinterpret_cast<float4*>(&xsb[0][(xrow + 32) * XS_STRIDE + xpg * 4]) = v1;
        if (lact) {
            float4 lv = *reinterpret_cast<const float4*>(
                Lam + (size_t)(pc + lrow) * n_out + q0 + lc4 * 4);
            *reinterpret_cast<float4*>(&lsb[0][lrow * QTILE + lc4 * 4]) = lv;
        }
    }
    __syncthreads();

    float acc1[4][QPER] = {};
    float acc2[4][QPER] = {};

    for (int c = 0; c < nchunk; ++c) {
        const int cur = c & 1;
        const bool hasnext = (c + 1 < nchunk);
        float4 nx0, nx1, nl;
        if (hasnext) {   // issue next-chunk global loads; latency hides under FMAs
            const int pc = pbase + (c + 1) * PCHUNK;
            nx0 = *reinterpret_cast<const float4*>(
                X + (size_t)(b0 + xrow) * n_in + pc + xpg * 4);
            nx1 = *reinterpret_cast<const float4*>(
                X + (size_t)(b0 + xrow + 32) * n_in + pc + xpg * 4);
            if (lact)
                nl = *reinterpret_cast<const float4*>(
                    Lam + (size_t)(pc + lrow) * n_out + q0 + lc4 * 4);
        }

        const float* xcur = xsb[cur];
        const float* lcur = lsb[cur];
        #pragma unroll
        for (int p = 0; p < PCHUNK; p += 4) {
            float4 xv[4];
            #pragma unroll
            for (int i = 0; i < 4; ++i)
                xv[i] = *reinterpret_cast<const float4*>(
                    &xcur[(bl * 4 + i) * XS_STRIDE + p]);

            float lvv[4][QPER];
            #pragma unroll
            for (int pp = 0; pp < 4; ++pp) {
                if (QPER == 2) {
                    float2 lw = *reinterpret_cast<const float2*>(
                        &lcur[(p + pp) * QTILE + qg * 2]);
                    lvv[pp][0] = lw.x; lvv[pp][1] = lw.y;
                } else {
                    lvv[pp][0] = lcur[(p + pp) * QTILE + qg];
                }
            }

            #pragma unroll
            for (int pp = 0; pp < 4; ++pp) {
                #pragma unroll
                for (int i = 0; i < 4; ++i) {
                    const float xe = (pp == 0) ? xv[i].x :
                                     (pp == 1) ? xv[i].y :
                                     (pp == 2) ? xv[i].z : xv[i].w;
                    #pragma unroll
                    for (int j = 0; j < QPER; ++j) {
                        const float s = xe + ee[j];
                        acc1[i][j] = fmaf(s,        lvv[pp][j], acc1[i][j]);
                        acc2[i][j] = fmaf(fabsf(s), lvv[pp][j], acc2[i][j]);
                    }
                }
            }
        }

        if (hasnext) {   // write next chunk into the other buffer
            const int nxt = cur ^ 1;
            *reinterpret_cast<float4*>(&xsb[nxt][xrow * XS_STRIDE + xpg * 4]) = nx0;
            *reinterpret_cast<float4*>(&xsb[nxt][(xrow + 32) * XS_STRIDE + xpg * 4]) = nx1;
            if (lact)
                *reinterpret_cast<float4*>(&lsb[nxt][lrow * QTILE + lc4 * 4]) = nl;
        }
        __syncthreads();
    }

    // epilogue: combine prelu halves, reduce across the two p-halves, store
    float o[4][QPER];
    #pragma unroll
    for (int i = 0; i < 4; ++i)
        #pragma unroll
        for (int j = 0; j < QPER; ++j)
            o[i][j] = c1 * acc1[i][j] + c2 * acc2[i][j];

    if (half == 1) {
        #pragma unroll
        for (int i = 0; i < 4; ++i)
            #pragma unroll
            for (int j = 0; j < QPER; ++j)
                red[(bl * 4 + i) * (QTILE + 1) + qg * QPER + j] = o[i][j];
    }
    __syncthreads();
    if (half == 0) {
        #pragma unroll
        for (int i = 0; i < 4; ++i) {
            #pragma unroll
            for (int j = 0; j < QPER; ++j)
                o[i][j] += red[(bl * 4 + i) * (QTILE + 1) + qg * QPER + j];
            float* dst = Y + (size_t)(b0 + bl * 4 + i) * n_out + q0 + qg * QPER;
            if (QPER == 2) {
                float2 st; st.x = o[i][0]; st.y = o[i][1];
                *reinterpret_cast<float2*>(dst) = st;
            } else {
                dst[0] = o[i][0];
            }
        }
    }
}

extern "C" void kernel_launch(void* const* d_in, const int* in_sizes, int n_in_args,
                              void* d_out, int out_size, void* d_ws, size_t ws_size,
                              hipStream_t stream)
{
    (void)n_in_args; (void)out_size; (void)ws_size;

    const float* x = (const float*)d_in[0];

    struct LayerP { const float *Lam, *Eps, *Aw; int n_in, n_out; };
    LayerP layers[4];
    for (int i = 0; i < 4; ++i) {
        layers[i].Lam   = (const float*)d_in[1 + 3 * i];
        layers[i].Eps   = (const float*)d_in[2 + 3 * i];
        layers[i].Aw    = (const float*)d_in[3 + 3 * i];
        layers[i].n_out = in_sizes[2 + 3 * i];
        layers[i].n_in  = in_sizes[1 + 3 * i] / layers[i].n_out;
    }
    const int B  = in_sizes[0] / layers[0].n_in;
    const int NB = B / 64;

    // ws: two 2MB ping-pong activation buffers (fp32), no partial buffers needed
    char* ws = (char*)d_ws;
    float* yA = (float*)ws;
    float* yB = (float*)(ws + (size_t)(4u << 20));

    const float* cur = x;
    for (int i = 0; i < 4; ++i) {
        const LayerP& ly = layers[i];
        float* Y = (i == 3) ? (float*)d_out : ((i % 2 == 0) ? yA : yB);

        // QPER=2 (QTILE 32) when n_out>=512 -> 16 q-tiles; QPER=1 (QTILE 16) for 256.
        if (ly.n_out >= 512) {
            dim3 grid((ly.n_out / 32) * NB), block(512);
            hipLaunchKernelGGL((gskan_layer_kernel<2>), grid, block, 0, stream,
                               cur, ly.Lam, ly.Eps, ly.Aw, Y, B, ly.n_in, ly.n_out, NB);
        } else {
            dim3 grid((ly.n_out / 16) * NB), block(512);
            hipLaunchKernelGGL((gskan_layer_kernel<1>), grid, block, 0, stream,
                               cur, ly.Lam, ly.Eps, ly.Aw, Y, B, ly.n_in, ly.n_out, NB);
        }
        cur = Y;
    }
}

// Round 10
// 123.719 us; speedup vs baseline: 1.8508x; 1.8508x over previous
//
#include <hip/hip_runtime.h>

// GSKAN layer: out[b,q] = sum_p prelu(x[b,p] + eps[q]) * Lam[p,q]
// prelu(s) = c1*s + c2*|s|,  c1 = (1+a)/2, c2 = (1-a)/2  (|s| = free VOP3 modifier)
//
// R10 = R6 (proven 117us) + XCD-aware block placement.
// R6 analysis: L0 re-fetched X ~8x from HBM (q-tiles sharing an X-tile land on
// different XCDs' private L2s) and was latency-bound on cold staging bursts.
// Fix: group blocks by z-slice (p-range). All (q,b) blocks of one z-class map
// to one XCD via tile = (g%8)*chunk + g/8 (XCD = hw blockIdx % 8 round-robin).
// Per XCD: X[:,z-range] fetched once (128-256KB), Lam[z-range,:] once (64-128KB);
// all reuse is L2-local. Every layer: exactly 1024 blocks = 4/CU (128/XCD).
// Inner loop / tile (64x64, thread 4x4, PCHUNK 32) unchanged from R6.

#define PCHUNK 32
#define XS_STRIDE 36   // 4 rows/thread -> 2-way bank alias only (free, m136)

__global__ __launch_bounds__(256) void gskan_partial_kernel(
    const float* __restrict__ X,     // [B][n_in]
    const float* __restrict__ Lam,   // [n_in][n_out]
    const float* __restrict__ Eps,   // [n_out]
    const float* __restrict__ Aw,    // [1]
    float* __restrict__ Part,        // [nsplit][B][n_out]
    int B, int n_in, int n_out, int p_per_split,
    int nq, int nb, int nsplit)
{
    __shared__ float xs[64 * XS_STRIDE];   // 9.2 KB
    __shared__ float ls[PCHUNK * 64];      // 8 KB  [p][q]

    // ---- XCD-aware decode: class = g&7 owns z ~ class (all q,b for that z) ----
    int q_tile, b_tile, zsp;
    {
        const int g = blockIdx.x;
        const int per_z = nq * nb;
        if ((nsplit & 7) == 0 || nsplit * per_z == 1024) {
            const int cls = g & 7;
            const int idx = g >> 3;
            zsp    = cls + 8 * (idx / per_z);
            const int r = idx % per_z;
            q_tile = r % nq;
            b_tile = r / nq;
        } else {           // fallback: plain decode
            zsp    = g / per_z;
            const int r = g % per_z;
            q_tile = r % nq;
            b_tile = r / nq;
        }
    }

    const int tid = threadIdx.x;
    const int qg  = tid & 15;   // q-group: thread owns q = q0 + qg*4 .. +3
    const int bl  = tid >> 4;   // b-group: rows b0 + bl*4 .. +3

    const int q0 = q_tile * 64;
    const int b0 = b_tile * 64;
    const int p_begin = zsp * p_per_split;
    int p_end = p_begin + p_per_split;
    if (p_end > n_in) p_end = n_in;

    const float a  = Aw[0];
    const float c1 = 0.5f * (1.0f + a);
    const float c2 = 0.5f * (1.0f - a);

    const float4 ev = *reinterpret_cast<const float4*>(Eps + q0 + qg * 4);
    const float ee[4] = {ev.x, ev.y, ev.z, ev.w};

    float acc1[4][4] = {};
    float acc2[4][4] = {};

    // hoisted stage addressing
    const int srowX = tid >> 3, spgX = tid & 7;    // X: rows 0..31 (+32 for r=1)
    const int srowL = tid >> 4, sc4L = tid & 15;   // Lam: rows 0..15 (+16 for r=1)

    for (int pc = p_begin; pc < p_end; pc += PCHUNK) {
        // stage X: 64 rows x 32 p = 512 float4, 2 per thread
        #pragma unroll
        for (int r = 0; r < 2; ++r) {
            const int row = srowX + r * 32;
            float4 v = *reinterpret_cast<const float4*>(
                X + (size_t)(b0 + row) * n_in + pc + spgX * 4);
            *reinterpret_cast<float4*>(&xs[row * XS_STRIDE + spgX * 4]) = v;
        }
        // stage Lam: 32 p x 64 q = 512 float4, 2 per thread
        #pragma unroll
        for (int r = 0; r < 2; ++r) {
            const int row = srowL + r * 16;
            float4 v = *reinterpret_cast<const float4*>(
                Lam + (size_t)(pc + row) * n_out + q0 + sc4L * 4);
            *reinterpret_cast<float4*>(&ls[row * 64 + sc4L * 4]) = v;
        }
        __syncthreads();

        #pragma unroll
        for (int p = 0; p < PCHUNK; p += 4) {
            float4 xv[4];
            #pragma unroll
            for (int i = 0; i < 4; ++i)
                xv[i] = *reinterpret_cast<const float4*>(&xs[(bl * 4 + i) * XS_STRIDE + p]);

            #pragma unroll
            for (int pp = 0; pp < 4; ++pp) {
                float4 lv = *reinterpret_cast<const float4*>(&ls[(p + pp) * 64 + qg * 4]);
                const float le[4] = {lv.x, lv.y, lv.z, lv.w};
                #pragma unroll
                for (int i = 0; i < 4; ++i) {
                    const float xe = (pp == 0) ? xv[i].x :
                                     (pp == 1) ? xv[i].y :
                                     (pp == 2) ? xv[i].z : xv[i].w;
                    #pragma unroll
                    for (int j = 0; j < 4; ++j) {
                        const float s = xe + ee[j];
                        acc1[i][j] = fmaf(s,        le[j], acc1[i][j]);
                        acc2[i][j] = fmaf(fabsf(s), le[j], acc2[i][j]);
                    }
                }
            }
        }
        __syncthreads();  // WAR: next chunk overwrites LDS
    }

    float* P = Part + (size_t)zsp * B * n_out;
    #pragma unroll
    for (int i = 0; i < 4; ++i) {
        const int b = b0 + bl * 4 + i;
        float4 o;
        o.x = c1 * acc1[i][0] + c2 * acc2[i][0];
        o.y = c1 * acc1[i][1] + c2 * acc2[i][1];
        o.z = c1 * acc1[i][2] + c2 * acc2[i][2];
        o.w = c1 * acc1[i][3] + c2 * acc2[i][3];
        *reinterpret_cast<float4*>(P + (size_t)b * n_out + q0 + qg * 4) = o;
    }
}

__global__ __launch_bounds__(256) void gskan_combine_kernel(
    const float* __restrict__ Part, float* __restrict__ Y, int n, int nsplit)
{
    int i = (blockIdx.x * 256 + threadIdx.x) * 4;
    if (i >= n) return;
    float4 acc = *reinterpret_cast<const float4*>(Part + i);
    for (int s = 1; s < nsplit; ++s) {
        float4 v = *reinterpret_cast<const float4*>(Part + (size_t)s * n + i);
        acc.x += v.x; acc.y += v.y; acc.z += v.z; acc.w += v.w;
    }
    *reinterpret_cast<float4*>(Y + i) = acc;
}

extern "C" void kernel_launch(void* const* d_in, const int* in_sizes, int n_in_args,
                              void* d_out, int out_size, void* d_ws, size_t ws_size,
                              hipStream_t stream)
{
    (void)n_in_args; (void)out_size;

    const float* x = (const float*)d_in[0];

    struct LayerP { const float *Lam, *Eps, *Aw; int n_in, n_out; };
    LayerP layers[4];
    for (int i = 0; i < 4; ++i) {
        layers[i].Lam   = (const float*)d_in[1 + 3 * i];
        layers[i].Eps   = (const float*)d_in[2 + 3 * i];
        layers[i].Aw    = (const float*)d_in[3 + 3 * i];
        layers[i].n_out = in_sizes[2 + 3 * i];
        layers[i].n_in  = in_sizes[1 + 3 * i] / layers[i].n_out;
    }
    const int B = in_sizes[0] / layers[0].n_in;

    // ws layout: [Part: 16MB][yA: 2MB][yB: 2MB]
    char* ws = (char*)d_ws;
    float* Part = (float*)ws;
    float* yA   = (float*)(ws + (size_t)(16u << 20));
    float* yB   = (float*)(ws + (size_t)(18u << 20));
    const bool have_ws = ws_size >= (size_t)(20u << 20);

    const float* cur = x;
    for (int i = 0; i < 4; ++i) {
        const LayerP& ly = layers[i];
        const int nq = ly.n_out / 64;
        const int nb = B / 64;

        int nsplit = 1;
        if (have_ws) {
            nsplit = 1024 / (nq * nb);              // exactly 1024 blocks = 4/CU
            if (nsplit < 1) nsplit = 1;
            int max_split = ly.n_in / PCHUNK;
            if (nsplit > max_split) nsplit = max_split;
        }
        int p_per = ((ly.n_in + nsplit * PCHUNK - 1) / (nsplit * PCHUNK)) * PCHUNK;
        nsplit = (ly.n_in + p_per - 1) / p_per;

        // Part capacity guard: nsplit * B * n_out floats must fit 16MB
        while ((size_t)nsplit * B * ly.n_out * 4 > ((size_t)16u << 20)) nsplit--;
        if (nsplit < 1) nsplit = 1;
        p_per = ((ly.n_in + nsplit * PCHUNK - 1) / (nsplit * PCHUNK)) * PCHUNK;
        nsplit = (ly.n_in + p_per - 1) / p_per;

        float* Y = (i == 3) ? (float*)d_out : ((i % 2 == 0) ? yA : yB);
        float* dst = (nsplit == 1) ? Y : Part;

        dim3 grid(nq * nb * nsplit), block(256);
        hipLaunchKernelGGL(gskan_partial_kernel, grid, block, 0, stream,
                           cur, ly.Lam, ly.Eps, ly.Aw, dst,
                           B, ly.n_in, ly.n_out, p_per, nq, nb, nsplit);

        if (nsplit > 1) {
            const int n = B * ly.n_out;
            dim3 cg((n / 4 + 255) / 256), cb(256);
            hipLaunchKernelGGL(gskan_combine_kernel, cg, cb, 0, stream, Part, Y, n, nsplit);
        }
        cur = Y;
    }
}